// Round 4
// baseline (808.934 us; speedup 1.0000x reference)
//
#include <hip/hip_runtime.h>
#include <hip/hip_bf16.h>

#define DEV static __device__ __forceinline__

typedef __attribute__((ext_vector_type(8))) _Float16 half8;   // A/B frag: 8 fp16 = 4 VGPR
typedef __attribute__((ext_vector_type(4))) float f32x4;      // C/D frag

constexpr int Bc = 4, Tc = 2048, Dc = 2048, Hc = 16;          // HD = 128

DEV ushort f2h(float f) { _Float16 h = (_Float16)f; return __builtin_bit_cast(ushort, h); }
DEV float  h2f(ushort u) { return (float)__builtin_bit_cast(_Float16, u); }

DEV f32x4 MFMA(half8 a, half8 b, f32x4 c) {
  return __builtin_amdgcn_mfma_f32_16x16x32_f16(a, b, c, 0, 0, 0);
}

DEV void async_cp16(void* lds, const void* g) {
  __builtin_amdgcn_global_load_lds((const __attribute__((address_space(1))) void*)g,
                                   (__attribute__((address_space(3))) void*)lds,
                                   16, 0, 0);
}

// ---------------- f32 -> fp16 convert ----------------
__global__ __launch_bounds__(256) void cvt(const float* __restrict__ in,
                                           ushort* __restrict__ out, int n4) {
  const int i = blockIdx.x * 256 + threadIdx.x;
  if (i >= n4) return;
  const float4 v = ((const float4*)in)[i];
  ushort4 o;
  o.x = f2h(v.x); o.y = f2h(v.y); o.z = f2h(v.z); o.w = f2h(v.w);
  ((ushort4*)out)[i] = o;
}

// ---------------- GEMM: C[m][n] = sum_k A[m][k] * W[n][k] ----------------
// 128x128 tile, BK=32, 4 waves (2x2), global_load_lds staging, 16 MFMA/K-step.
template <typename OutT>
__global__ __launch_bounds__(256) void gemm_bt(const ushort* __restrict__ A,
                                               const ushort* __restrict__ Bw,
                                               OutT* __restrict__ C) {
  __shared__ ushort As[128 * 32];
  __shared__ ushort Bs[128 * 32];
  const int tid = threadIdx.x;
  const int lane = tid & 63, wid = tid >> 6;
  const int g = lane >> 4, q16 = lane & 15;
  const int wm = wid >> 1, wn = wid & 1;
  const int bm = blockIdx.y, bn = blockIdx.x;
  const ushort* Ab = A + (size_t)bm * 128 * Dc;
  const ushort* Bb = Bw + (size_t)bn * 128 * Dc;

  f32x4 acc[4][4] = {};

  for (int k0 = 0; k0 < Dc; k0 += 32) {
    __syncthreads();
#pragma unroll
    for (int q = 0; q < 2; ++q) {
      const int c = q * 256 + tid;
      const int row = c >> 2, col = (c & 3) << 3;
      const int ldsbase = (q * 256 + wid * 64) * 8;
      async_cp16(&As[ldsbase], Ab + (size_t)row * Dc + k0 + col);
      async_cp16(&Bs[ldsbase], Bb + (size_t)row * Dc + k0 + col);
    }
    __syncthreads();
    half8 a[4], b[4];
#pragma unroll
    for (int i = 0; i < 4; ++i)
      a[i] = *(const half8*)&As[(wm * 64 + i * 16 + q16) * 32 + g * 8];
#pragma unroll
    for (int j = 0; j < 4; ++j)
      b[j] = *(const half8*)&Bs[(wn * 64 + j * 16 + q16) * 32 + g * 8];
#pragma unroll
    for (int i = 0; i < 4; ++i)
#pragma unroll
      for (int j = 0; j < 4; ++j)
        acc[i][j] = MFMA(a[i], b[j], acc[i][j]);
  }

  const int m00 = bm * 128 + wm * 64 + g * 4;
  const int n0 = bn * 128 + wn * 64 + q16;
#pragma unroll
  for (int i = 0; i < 4; ++i)
#pragma unroll
    for (int j = 0; j < 4; ++j) {
      const int m0 = m00 + i * 16;
      const int n = n0 + j * 16;
#pragma unroll
      for (int r = 0; r < 4; ++r) {
        const float v = acc[i][j][r];
        if constexpr (sizeof(OutT) == 2)
          C[(size_t)(m0 + r) * Dc + n] = (OutT)f2h(v);
        else
          C[(size_t)(m0 + r) * Dc + n] = (OutT)v;
      }
    }
}

// ---------------- RoPE in-place on [B,T,H,128] fp16 ----------------
__global__ __launch_bounds__(256) void rope(ushort* __restrict__ X,
                                            const float* __restrict__ cs,
                                            const float* __restrict__ sn) {
  const int tid = blockIdx.x * 256 + threadIdx.x;
  const int row = tid >> 4;
  const int jq = (tid & 15) << 2;
  const int t = (row >> 4) & (Tc - 1);
  ushort* base = X + (size_t)row * 128;
  const ushort4 lo = *(const ushort4*)(base + jq);
  const ushort4 hi = *(const ushort4*)(base + 64 + jq);
  const float4 c4 = *(const float4*)(cs + t * 128 + jq);
  const float4 s4 = *(const float4*)(sn + t * 128 + jq);
  const float xl[4] = {h2f(lo.x), h2f(lo.y), h2f(lo.z), h2f(lo.w)};
  const float xh[4] = {h2f(hi.x), h2f(hi.y), h2f(hi.z), h2f(hi.w)};
  const float cc[4] = {c4.x, c4.y, c4.z, c4.w};
  const float ss[4] = {s4.x, s4.y, s4.z, s4.w};
  ushort4 olo, ohi;
  ushort* po = (ushort*)&olo;
  ushort* ph = (ushort*)&ohi;
#pragma unroll
  for (int k = 0; k < 4; ++k) {
    po[k] = f2h(xl[k] * cc[k] - xh[k] * ss[k]);
    ph[k] = f2h(xh[k] * cc[k] + xl[k] * ss[k]);
  }
  *(ushort4*)(base + jq) = olo;
  *(ushort4*)(base + 64 + jq) = ohi;
}

// ---------------- causal flash attention ----------------
// grid (8, 64), 512-thread blocks: 8 waves x 16 q-rows = 128-row q-tile.
// Paired q-tiles {15-bx, bx} -> uniform 34 kv-iters. VGPR capped at 128
// (launch_bounds 512,4) -> 4 waves/SIMD, 16 waves/CU (2 blocks, LDS 80KB).
// K direct-to-LDS w/ pre-swizzled source; V reg-staged transpose, T14 split.
__global__ __launch_bounds__(512, 4) void attn(const ushort* __restrict__ Q,
                                               const ushort* __restrict__ K,
                                               const ushort* __restrict__ V,
                                               ushort* __restrict__ O) {
  __shared__ ushort Ks[2][64 * 128];   // [kv][d], XOR-swizzled (granule ^= kv&7)
  __shared__ ushort Vt[2][128 * 64];   // [d][kv], XOR-swizzled rows
  __shared__ ushort Pt[8][16 * 64];    // per-wave [q][kv], XOR-swizzled rows

  const int tid = threadIdx.x;         // 0..511
  const int lane = tid & 63, wid = tid >> 6;   // wid 0..7
  const int g = lane >> 4, q16 = lane & 15;
  const int bh = blockIdx.y;
  const int b = bh >> 4, h = bh & 15;
  const size_t headbase = ((size_t)b * Tc * Hc + h) * 128;  // t-stride = 2048
  const float SCL2 = 0.12751743f;      // log2(e)/sqrt(128)

  uint4 vreg[2];

#define ISSUEK(KT, BUF) do {                                                   \
    const ushort* Kb_ = K + headbase + (size_t)(KT) * 64 * Dc;                 \
    _Pragma("unroll") for (int i_ = 0; i_ < 2; ++i_) {                         \
      const int c_ = i_ * 512 + tid;                                           \
      const int kv_ = c_ >> 4, gl_ = c_ & 15;                                  \
      async_cp16(&Ks[BUF][(i_ * 512 + wid * 64) * 8],                          \
                 Kb_ + (size_t)kv_ * Dc + ((gl_ ^ (kv_ & 7)) << 3));           \
    }                                                                          \
  } while (0)

#define LOADV(KT) do {                                                         \
    const ushort* Vb_ = V + headbase + (size_t)(KT) * 64 * Dc;                 \
    const int kvp_ = tid >> 4, dc_ = tid & 15;                                 \
    const ushort* p0_ = Vb_ + (size_t)(2 * kvp_) * Dc + dc_ * 8;               \
    vreg[0] = *(const uint4*)p0_;                                              \
    vreg[1] = *(const uint4*)(p0_ + Dc);                                       \
  } while (0)

#define WRITEV(BUF) do {                                                       \
    const int kvp_ = tid >> 4, dc_ = tid & 15;                                 \
    const ushort* e0_ = (const ushort*)&vreg[0];                               \
    const ushort* e1_ = (const ushort*)&vreg[1];                               \
    _Pragma("unroll") for (int j_ = 0; j_ < 8; ++j_) {                         \
      const int d_ = dc_ * 8 + j_;                                             \
      const unsigned w_ = (unsigned)e0_[j_] | ((unsigned)e1_[j_] << 16);       \
      *(unsigned*)&Vt[BUF][(d_ * 64 + 2 * kvp_) ^ ((d_ & 7) << 3)] = w_;       \
    }                                                                          \
  } while (0)

#pragma unroll 1
  for (int half = 0; half < 2; ++half) {
    const int q0 = (half ? (int)blockIdx.x : 15 - (int)blockIdx.x) * 128;
    const int qrow = q0 + wid * 16;
    const int nt = q0 / 64 + 2;

    // Q fragments (B-op: col=q=lane&15, k=d=g*8+j)
    half8 qreg[4];
#pragma unroll
    for (int ds = 0; ds < 4; ++ds)
      qreg[ds] = *(const half8*)(Q + headbase +
                 (size_t)(qrow + q16) * Dc + ds * 32 + g * 8);

    f32x4 oacc[8] = {};                // O^T frags: row=d (g*4+r), col=q
    float m_ = -1e30f, l_ = 0.f;

    __builtin_amdgcn_s_barrier();      // prior half done reading all LDS bufs
    __builtin_amdgcn_sched_barrier(0);
    ISSUEK(0, 0);
    LOADV(0);
    WRITEV(0);                         // compiler waits vmcnt for vreg here

#pragma unroll 1
    for (int kt = 0; kt < nt; ++kt) {
      const int cur = kt & 1;
      const int kv0 = kt * 64;
      asm volatile("s_waitcnt vmcnt(0) lgkmcnt(0)" ::: "memory");
      __builtin_amdgcn_s_barrier();
      __builtin_amdgcn_sched_barrier(0);
      if (kt + 1 < nt) {
        ISSUEK(kt + 1, cur ^ 1);
        LOADV(kt + 1);
      }

      if (kv0 <= qrow + 15) {
        const ushort* Ksb = Ks[cur];
        const ushort* Vtb = Vt[cur];
        // S^T = K Q^T
        f32x4 s[4] = {};
        __builtin_amdgcn_s_setprio(1);
#pragma unroll
        for (int ds = 0; ds < 4; ++ds) {
          half8 kf[4];
#pragma unroll
          for (int kvf = 0; kvf < 4; ++kvf) {
            const int kv = kvf * 16 + q16;
            kf[kvf] = *(const half8*)&Ksb[(kv * 128 + ds * 32 + g * 8) ^ ((kv & 7) << 3)];
          }
#pragma unroll
          for (int kvf = 0; kvf < 4; ++kvf)
            s[kvf] = MFMA(kf[kvf], qreg[ds], s[kvf]);
        }
        __builtin_amdgcn_s_setprio(0);
        // causal mask + running max (q = qrow+q16; kv = kv0+kvf*16+g*4+r)
        const bool notfull = (kv0 + 63) > qrow;
        const int qg = qrow + q16;
        float pmax = -1e30f;
#pragma unroll
        for (int kvf = 0; kvf < 4; ++kvf)
#pragma unroll
          for (int r = 0; r < 4; ++r) {
            float v = s[kvf][r];
            if (notfull && (kv0 + kvf * 16 + g * 4 + r) > qg) v = -1e30f;
            s[kvf][r] = v;
            pmax = fmaxf(pmax, v);
          }
        pmax = fmaxf(pmax, __shfl_xor(pmax, 16));
        pmax = fmaxf(pmax, __shfl_xor(pmax, 32));
        const float mn = fmaxf(m_, pmax);
        const float alpha = __builtin_exp2f((m_ - mn) * SCL2);
        m_ = mn;
        float lsum = 0.f;
        ushort* Ptw = Pt[wid];
#pragma unroll
        for (int kvf = 0; kvf < 4; ++kvf) {
          const float p0 = __builtin_exp2f((s[kvf][0] - mn) * SCL2);
          const float p1 = __builtin_exp2f((s[kvf][1] - mn) * SCL2);
          const float p2 = __builtin_exp2f((s[kvf][2] - mn) * SCL2);
          const float p3 = __builtin_exp2f((s[kvf][3] - mn) * SCL2);
          lsum += (p0 + p1) + (p2 + p3);
          uint2 pk;
          pk.x = (unsigned)f2h(p0) | ((unsigned)f2h(p1) << 16);
          pk.y = (unsigned)f2h(p2) | ((unsigned)f2h(p3) << 16);
          *(uint2*)&Ptw[(q16 * 64 + kvf * 16 + g * 4) ^ ((q16 & 7) << 3)] = pk;
        }
        lsum += __shfl_xor(lsum, 16);
        lsum += __shfl_xor(lsum, 32);
        l_ = l_ * alpha + lsum;
#pragma unroll
        for (int df = 0; df < 8; ++df)
          oacc[df] *= alpha;
        // O^T += V^T P^T
        __builtin_amdgcn_s_setprio(1);
#pragma unroll
        for (int c = 0; c < 2; ++c) {
          const half8 pb = *(const half8*)&Ptw[(q16 * 64 + c * 32 + g * 8) ^ ((q16 & 7) << 3)];
#pragma unroll
          for (int df = 0; df < 8; ++df) {
            const int d = df * 16 + q16;
            const half8 vf = *(const half8*)&Vtb[(d * 64 + c * 32 + g * 8) ^ ((d & 7) << 3)];
            oacc[df] = MFMA(vf, pb, oacc[df]);
          }
        }
        __builtin_amdgcn_s_setprio(0);
      }

      if (kt + 1 < nt) WRITEV(cur ^ 1);   // vreg vmcnt wait lands here, hidden
    }

    // epilogue: O[b][t][h][d] fp16
    {
      const float inv = 1.0f / l_;
      const int t = qrow + q16;
#pragma unroll
      for (int df = 0; df < 8; ++df) {
        const f32x4 v = oacc[df];
        ushort4 o;
        o.x = f2h(v[0] * inv); o.y = f2h(v[1] * inv);
        o.z = f2h(v[2] * inv); o.w = f2h(v[3] * inv);
        *(ushort4*)(O + headbase + (size_t)t * Dc + df * 16 + g * 4) = o;
      }
    }
  }
#undef ISSUEK
#undef LOADV
#undef WRITEV
}

extern "C" void kernel_launch(void* const* d_in, const int* in_sizes, int n_in,
                              void* d_out, int out_size, void* d_ws, size_t ws_size,
                              hipStream_t stream) {
  (void)in_sizes; (void)n_in; (void)out_size; (void)ws_size;
  const float* x  = (const float*)d_in[0];
  const float* cs = (const float*)d_in[1];
  const float* sn = (const float*)d_in[2];
  // d_in[3] = mask (unused: causal handled analytically)
  const float* Wq = (const float*)d_in[4];
  const float* Wk = (const float*)d_in[5];
  const float* Wv = (const float*)d_in[6];
  const float* Wo = (const float*)d_in[7];
  float* out = (float*)d_out;

  char* ws = (char*)d_ws;
  const size_t MB = 1024 * 1024;
  ushort* xb  = (ushort*)(ws);            // 32MB x fp16; reused as attn output O
  ushort* wqb = (ushort*)(ws + 32 * MB);
  ushort* wkb = (ushort*)(ws + 40 * MB);
  ushort* wvb = (ushort*)(ws + 48 * MB);
  ushort* wob = (ushort*)(ws + 56 * MB);
  ushort* Qr  = (ushort*)(ws + 64 * MB);  // 32MB each, [B,T,H,128] fp16
  ushort* Kr  = (ushort*)(ws + 96 * MB);
  ushort* Vr  = (ushort*)(ws + 128 * MB); // end: 160MB

  cvt<<<16384, 256, 0, stream>>>(x, xb, 4194304);
  cvt<<<4096, 256, 0, stream>>>(Wq, wqb, 1048576);
  cvt<<<4096, 256, 0, stream>>>(Wk, wkb, 1048576);
  cvt<<<4096, 256, 0, stream>>>(Wv, wvb, 1048576);
  cvt<<<4096, 256, 0, stream>>>(Wo, wob, 1048576);

  const dim3 gg(16, 64);
  gemm_bt<ushort><<<gg, 256, 0, stream>>>(xb, wqb, Qr);
  gemm_bt<ushort><<<gg, 256, 0, stream>>>(xb, wkb, Kr);
  gemm_bt<ushort><<<gg, 256, 0, stream>>>(xb, wvb, Vr);

  rope<<<8192, 256, 0, stream>>>(Qr, cs, sn);
  rope<<<8192, 256, 0, stream>>>(Kr, cs, sn);

  attn<<<dim3(8, 64), 512, 0, stream>>>(Qr, Kr, Vr, xb);

  gemm_bt<float><<<gg, 256, 0, stream>>>(xb, wob, out);
}

// Round 5
// 654.720 us; speedup vs baseline: 1.2355x; 1.2355x over previous
//
#include <hip/hip_runtime.h>
#include <hip/hip_bf16.h>

#define DEV static __device__ __forceinline__

typedef __attribute__((ext_vector_type(8))) _Float16 half8;   // A/B frag: 8 fp16 = 4 VGPR
typedef __attribute__((ext_vector_type(4))) float f32x4;      // C/D frag

constexpr int Bc = 4, Tc = 2048, Dc = 2048, Hc = 16;          // HD = 128

DEV ushort f2h(float f) { _Float16 h = (_Float16)f; return __builtin_bit_cast(ushort, h); }
DEV float  h2f(ushort u) { return (float)__builtin_bit_cast(_Float16, u); }

DEV f32x4 MFMA(half8 a, half8 b, f32x4 c) {
  return __builtin_amdgcn_mfma_f32_16x16x32_f16(a, b, c, 0, 0, 0);
}

DEV void async_cp16(void* lds, const void* g) {
  __builtin_amdgcn_global_load_lds((const __attribute__((address_space(1))) void*)g,
                                   (__attribute__((address_space(3))) void*)lds,
                                   16, 0, 0);
}

// ---------------- f32 -> fp16 convert ----------------
__global__ __launch_bounds__(256) void cvt(const float* __restrict__ in,
                                           ushort* __restrict__ out, int n4) {
  const int i = blockIdx.x * 256 + threadIdx.x;
  if (i >= n4) return;
  const float4 v = ((const float4*)in)[i];
  ushort4 o;
  o.x = f2h(v.x); o.y = f2h(v.y); o.z = f2h(v.z); o.w = f2h(v.w);
  ((ushort4*)out)[i] = o;
}

// ---------------- GEMM: C[m][n] = sum_k A[m][k] * W[n][k] ----------------
// 128x128 tile, BK=32, 4 waves (2x2), global_load_lds staging, 16 MFMA/K-step.
template <typename OutT>
__global__ __launch_bounds__(256) void gemm_bt(const ushort* __restrict__ A,
                                               const ushort* __restrict__ Bw,
                                               OutT* __restrict__ C) {
  __shared__ ushort As[128 * 32];
  __shared__ ushort Bs[128 * 32];
  const int tid = threadIdx.x;
  const int lane = tid & 63, wid = tid >> 6;
  const int g = lane >> 4, q16 = lane & 15;
  const int wm = wid >> 1, wn = wid & 1;
  const int bm = blockIdx.y, bn = blockIdx.x;
  const ushort* Ab = A + (size_t)bm * 128 * Dc;
  const ushort* Bb = Bw + (size_t)bn * 128 * Dc;

  f32x4 acc[4][4] = {};

  for (int k0 = 0; k0 < Dc; k0 += 32) {
    __syncthreads();
#pragma unroll
    for (int q = 0; q < 2; ++q) {
      const int c = q * 256 + tid;
      const int row = c >> 2, col = (c & 3) << 3;
      const int ldsbase = (q * 256 + wid * 64) * 8;
      async_cp16(&As[ldsbase], Ab + (size_t)row * Dc + k0 + col);
      async_cp16(&Bs[ldsbase], Bb + (size_t)row * Dc + k0 + col);
    }
    __syncthreads();
    half8 a[4], b[4];
#pragma unroll
    for (int i = 0; i < 4; ++i)
      a[i] = *(const half8*)&As[(wm * 64 + i * 16 + q16) * 32 + g * 8];
#pragma unroll
    for (int j = 0; j < 4; ++j)
      b[j] = *(const half8*)&Bs[(wn * 64 + j * 16 + q16) * 32 + g * 8];
#pragma unroll
    for (int i = 0; i < 4; ++i)
#pragma unroll
      for (int j = 0; j < 4; ++j)
        acc[i][j] = MFMA(a[i], b[j], acc[i][j]);
  }

  const int m00 = bm * 128 + wm * 64 + g * 4;
  const int n0 = bn * 128 + wn * 64 + q16;
#pragma unroll
  for (int i = 0; i < 4; ++i)
#pragma unroll
    for (int j = 0; j < 4; ++j) {
      const int m0 = m00 + i * 16;
      const int n = n0 + j * 16;
#pragma unroll
      for (int r = 0; r < 4; ++r) {
        const float v = acc[i][j][r];
        if constexpr (sizeof(OutT) == 2)
          C[(size_t)(m0 + r) * Dc + n] = (OutT)f2h(v);
        else
          C[(size_t)(m0 + r) * Dc + n] = (OutT)v;
      }
    }
}

// ---------------- RoPE in-place on [B,T,H,128] fp16 ----------------
__global__ __launch_bounds__(256) void rope(ushort* __restrict__ X,
                                            const float* __restrict__ cs,
                                            const float* __restrict__ sn) {
  const int tid = blockIdx.x * 256 + threadIdx.x;
  const int row = tid >> 4;
  const int jq = (tid & 15) << 2;
  const int t = (row >> 4) & (Tc - 1);
  ushort* base = X + (size_t)row * 128;
  const ushort4 lo = *(const ushort4*)(base + jq);
  const ushort4 hi = *(const ushort4*)(base + 64 + jq);
  const float4 c4 = *(const float4*)(cs + t * 128 + jq);
  const float4 s4 = *(const float4*)(sn + t * 128 + jq);
  const float xl[4] = {h2f(lo.x), h2f(lo.y), h2f(lo.z), h2f(lo.w)};
  const float xh[4] = {h2f(hi.x), h2f(hi.y), h2f(hi.z), h2f(hi.w)};
  const float cc[4] = {c4.x, c4.y, c4.z, c4.w};
  const float ss[4] = {s4.x, s4.y, s4.z, s4.w};
  ushort4 olo, ohi;
  ushort* po = (ushort*)&olo;
  ushort* ph = (ushort*)&ohi;
#pragma unroll
  for (int k = 0; k < 4; ++k) {
    po[k] = f2h(xl[k] * cc[k] - xh[k] * ss[k]);
    ph[k] = f2h(xh[k] * cc[k] + xl[k] * ss[k]);
  }
  *(ushort4*)(base + jq) = olo;
  *(ushort4*)(base + 64 + jq) = ohi;
}

// ---------------- causal flash attention ----------------
// grid (8, 64) = 512 blocks, 512 threads (8 waves x 16 q-rows = 128-row tile).
// Head-major XCD swizzle: flat%8 picks the XCD (dispatch round-robin), so each
// XCD owns 8 whole heads -> K/V panels stay in that XCD's L2.
// Paired q-tiles {15-qx, qx} -> uniform 36 kv-iters. launch_bounds(512,2):
// 256-reg cap (~no spills), 2 waves/SIMD. K direct-to-LDS w/ pre-swizzled
// source; V reg-staged transpose (4-way-max conflict lane map), T14 split.
__global__ __launch_bounds__(512, 2) void attn(const ushort* __restrict__ Q,
                                               const ushort* __restrict__ K,
                                               const ushort* __restrict__ V,
                                               ushort* __restrict__ O) {
  __shared__ ushort Ks[2][64 * 128];   // [kv][d], XOR-swizzled (granule ^= kv&7)
  __shared__ ushort Vt[2][128 * 64];   // [d][kv], XOR-swizzled rows
  __shared__ ushort Pt[8][16 * 64];    // per-wave [q][kv], XOR-swizzled rows

  const int tid = threadIdx.x;         // 0..511
  const int lane = tid & 63, wid = tid >> 6;   // wid 0..7
  const int g = lane >> 4, q16 = lane & 15;

  // head-major XCD swizzle: bijective (8,64) remap
  const int flat = (int)(blockIdx.x + 8 * blockIdx.y);
  const int xcd = flat & 7, idx = flat >> 3;          // idx 0..63
  const int bh = xcd + 8 * (idx & 7);                 // head-slot 0..63
  const int qx = idx >> 3;                            // q-tile pair id 0..7

  const int b = bh >> 4, h = bh & 15;
  const size_t headbase = ((size_t)b * Tc * Hc + h) * 128;  // t-stride = 2048
  const float SCL2 = 0.12751743f;      // log2(e)/sqrt(128)

  // V lane mapping: dc (column-group) spans only 4 values per wave -> 4-way
  // max on Vt ds_writes; kvp spans 16 -> distinct banks.
  const int vdc = (wid & 3) * 4 + (lane & 3);         // 0..15: d = vdc*8..+7
  const int vkvp = (wid >> 2) * 16 + (lane >> 2);     // 0..31: kv pair

  uint4 vreg[2];

#define ISSUEK(KT, BUF) do {                                                   \
    const ushort* Kb_ = K + headbase + (size_t)(KT) * 64 * Dc;                 \
    _Pragma("unroll") for (int i_ = 0; i_ < 2; ++i_) {                         \
      const int c_ = i_ * 512 + tid;                                           \
      const int kv_ = c_ >> 4, gl_ = c_ & 15;                                  \
      async_cp16(&Ks[BUF][(i_ * 512 + wid * 64) * 8],                          \
                 Kb_ + (size_t)kv_ * Dc + ((gl_ ^ (kv_ & 7)) << 3));           \
    }                                                                          \
  } while (0)

#define LOADV(KT) do {                                                         \
    const ushort* p0_ = V + headbase + (size_t)((KT) * 64 + 2 * vkvp) * Dc +   \
                        vdc * 8;                                               \
    vreg[0] = *(const uint4*)p0_;                                              \
    vreg[1] = *(const uint4*)(p0_ + Dc);                                       \
  } while (0)

#define WRITEV(BUF) do {                                                       \
    const ushort* e0_ = (const ushort*)&vreg[0];                               \
    const ushort* e1_ = (const ushort*)&vreg[1];                               \
    _Pragma("unroll") for (int j_ = 0; j_ < 8; ++j_) {                         \
      const int d_ = vdc * 8 + j_;                                             \
      const unsigned w_ = (unsigned)e0_[j_] | ((unsigned)e1_[j_] << 16);       \
      *(unsigned*)&Vt[BUF][(d_ * 64 + 2 * vkvp) ^ ((d_ & 7) << 3)] = w_;       \
    }                                                                          \
  } while (0)

#pragma unroll 1
  for (int half = 0; half < 2; ++half) {
    const int q0 = (half ? qx : 15 - qx) * 128;
    const int qrow = q0 + wid * 16;
    const int nt = q0 / 64 + 2;

    // Q fragments (B-op: col=q=lane&15, k=d=g*8+j)
    half8 qreg[4];
#pragma unroll
    for (int ds = 0; ds < 4; ++ds)
      qreg[ds] = *(const half8*)(Q + headbase +
                 (size_t)(qrow + q16) * Dc + ds * 32 + g * 8);

    f32x4 oacc[8] = {};                // O^T frags: row=d (g*4+r), col=q
    float m_ = -1e30f, l_ = 0.f;

    __builtin_amdgcn_s_barrier();      // prior half done reading all LDS bufs
    __builtin_amdgcn_sched_barrier(0);
    ISSUEK(0, 0);
    LOADV(0);
    WRITEV(0);                         // compiler waits vmcnt for vreg here

#pragma unroll 1
    for (int kt = 0; kt < nt; ++kt) {
      const int cur = kt & 1;
      const int kv0 = kt * 64;
      asm volatile("s_waitcnt vmcnt(0) lgkmcnt(0)" ::: "memory");
      __builtin_amdgcn_s_barrier();
      __builtin_amdgcn_sched_barrier(0);
      if (kt + 1 < nt) {
        ISSUEK(kt + 1, cur ^ 1);
        LOADV(kt + 1);
      }

      if (kv0 <= qrow + 15) {
        const ushort* Ksb = Ks[cur];
        const ushort* Vtb = Vt[cur];
        // S^T = K Q^T
        f32x4 s[4] = {};
        __builtin_amdgcn_s_setprio(1);
#pragma unroll
        for (int ds = 0; ds < 4; ++ds) {
          half8 kf[4];
#pragma unroll
          for (int kvf = 0; kvf < 4; ++kvf) {
            const int kv = kvf * 16 + q16;
            kf[kvf] = *(const half8*)&Ksb[(kv * 128 + ds * 32 + g * 8) ^ ((kv & 7) << 3)];
          }
#pragma unroll
          for (int kvf = 0; kvf < 4; ++kvf)
            s[kvf] = MFMA(kf[kvf], qreg[ds], s[kvf]);
        }
        __builtin_amdgcn_s_setprio(0);
        // causal mask + running max (q = qrow+q16; kv = kv0+kvf*16+g*4+r)
        const bool notfull = (kv0 + 63) > qrow;
        const int qg = qrow + q16;
        float pmax = -1e30f;
#pragma unroll
        for (int kvf = 0; kvf < 4; ++kvf)
#pragma unroll
          for (int r = 0; r < 4; ++r) {
            float v = s[kvf][r];
            if (notfull && (kv0 + kvf * 16 + g * 4 + r) > qg) v = -1e30f;
            s[kvf][r] = v;
            pmax = fmaxf(pmax, v);
          }
        pmax = fmaxf(pmax, __shfl_xor(pmax, 16));
        pmax = fmaxf(pmax, __shfl_xor(pmax, 32));
        const float mn = fmaxf(m_, pmax);
        const float alpha = __builtin_exp2f((m_ - mn) * SCL2);
        m_ = mn;
        float lsum = 0.f;
        ushort* Ptw = Pt[wid];
#pragma unroll
        for (int kvf = 0; kvf < 4; ++kvf) {
          const float p0 = __builtin_exp2f((s[kvf][0] - mn) * SCL2);
          const float p1 = __builtin_exp2f((s[kvf][1] - mn) * SCL2);
          const float p2 = __builtin_exp2f((s[kvf][2] - mn) * SCL2);
          const float p3 = __builtin_exp2f((s[kvf][3] - mn) * SCL2);
          lsum += (p0 + p1) + (p2 + p3);
          uint2 pk;
          pk.x = (unsigned)f2h(p0) | ((unsigned)f2h(p1) << 16);
          pk.y = (unsigned)f2h(p2) | ((unsigned)f2h(p3) << 16);
          *(uint2*)&Ptw[(q16 * 64 + kvf * 16 + g * 4) ^ ((q16 & 7) << 3)] = pk;
        }
        lsum += __shfl_xor(lsum, 16);
        lsum += __shfl_xor(lsum, 32);
        l_ = l_ * alpha + lsum;
#pragma unroll
        for (int df = 0; df < 8; ++df)
          oacc[df] *= alpha;
        // O^T += V^T P^T
        __builtin_amdgcn_s_setprio(1);
#pragma unroll
        for (int c = 0; c < 2; ++c) {
          const half8 pb = *(const half8*)&Ptw[(q16 * 64 + c * 32 + g * 8) ^ ((q16 & 7) << 3)];
#pragma unroll
          for (int df = 0; df < 8; ++df) {
            const int d = df * 16 + q16;
            const half8 vf = *(const half8*)&Vtb[(d * 64 + c * 32 + g * 8) ^ ((d & 7) << 3)];
            oacc[df] = MFMA(vf, pb, oacc[df]);
          }
        }
        __builtin_amdgcn_s_setprio(0);
      }

      if (kt + 1 < nt) WRITEV(cur ^ 1);   // vreg vmcnt wait lands here, hidden
    }

    // epilogue: O[b][t][h][d] fp16
    {
      const float inv = 1.0f / l_;
      const int t = qrow + q16;
#pragma unroll
      for (int df = 0; df < 8; ++df) {
        const f32x4 v = oacc[df];
        ushort4 o;
        o.x = f2h(v[0] * inv); o.y = f2h(v[1] * inv);
        o.z = f2h(v[2] * inv); o.w = f2h(v[3] * inv);
        *(ushort4*)(O + headbase + (size_t)t * Dc + df * 16 + g * 4) = o;
      }
    }
  }
#undef ISSUEK
#undef LOADV
#undef WRITEV
}

extern "C" void kernel_launch(void* const* d_in, const int* in_sizes, int n_in,
                              void* d_out, int out_size, void* d_ws, size_t ws_size,
                              hipStream_t stream) {
  (void)in_sizes; (void)n_in; (void)out_size; (void)ws_size;
  const float* x  = (const float*)d_in[0];
  const float* cs = (const float*)d_in[1];
  const float* sn = (const float*)d_in[2];
  // d_in[3] = mask (unused: causal handled analytically)
  const float* Wq = (const float*)d_in[4];
  const float* Wk = (const float*)d_in[5];
  const float* Wv = (const float*)d_in[6];
  const float* Wo = (const float*)d_in[7];
  float* out = (float*)d_out;

  char* ws = (char*)d_ws;
  const size_t MB = 1024 * 1024;
  ushort* xb  = (ushort*)(ws);            // 32MB x fp16; reused as attn output O
  ushort* wqb = (ushort*)(ws + 32 * MB);
  ushort* wkb = (ushort*)(ws + 40 * MB);
  ushort* wvb = (ushort*)(ws + 48 * MB);
  ushort* wob = (ushort*)(ws + 56 * MB);
  ushort* Qr  = (ushort*)(ws + 64 * MB);  // 32MB each, [B,T,H,128] fp16
  ushort* Kr  = (ushort*)(ws + 96 * MB);
  ushort* Vr  = (ushort*)(ws + 128 * MB); // end: 160MB

  cvt<<<16384, 256, 0, stream>>>(x, xb, 4194304);
  cvt<<<4096, 256, 0, stream>>>(Wq, wqb, 1048576);
  cvt<<<4096, 256, 0, stream>>>(Wk, wkb, 1048576);
  cvt<<<4096, 256, 0, stream>>>(Wv, wvb, 1048576);
  cvt<<<4096, 256, 0, stream>>>(Wo, wob, 1048576);

  const dim3 gg(16, 64);
  gemm_bt<ushort><<<gg, 256, 0, stream>>>(xb, wqb, Qr);
  gemm_bt<ushort><<<gg, 256, 0, stream>>>(xb, wkb, Kr);
  gemm_bt<ushort><<<gg, 256, 0, stream>>>(xb, wvb, Vr);

  rope<<<8192, 256, 0, stream>>>(Qr, cs, sn);
  rope<<<8192, 256, 0, stream>>>(Kr, cs, sn);

  attn<<<dim3(8, 64), 512, 0, stream>>>(Qr, Kr, Vr, xb);

  gemm_bt<float><<<gg, 256, 0, stream>>>(xb, wob, out);
}